// Round 9
// baseline (292.628 us; speedup 1.0000x reference)
//
#include <hip/hip_runtime.h>
#include <hip/hip_bf16.h>

// CoreAttention (ChatGLM GQA fallback) — barrier-free split-KV flash attn.
// Prepass packs K and V into MFMA-A-fragment-ordered bf16 images in d_ws;
// main loop: 4 waves share 32 q rows, each owns a kv-quarter (16 tiles of 32),
// loads K/V fragments coalesced global->VGPR (no LDS, no barriers), mask via
// r7-proven volatile-asm gather. Fixed-shift softmax (scores bounded) makes
// cross-wave combine a plain sum: one-time 32KB LDS reduction at the end.
// Counted-vmcnt pipeline: per tile, queue = [K8][M4][V8], never drained to 0
// mid-loop; loop-exit drain + pin ALL asm-load dests (r5/r6 lesson).
// B=2, H=32, G=2, Q=KV=2048, D=128, fp32 in/out.

constexpr int Bn = 2, Hn = 32, Gn = 2, Qn = 2048, KVn = 2048, Dn = 128;
constexpr int WARPS = 4, QBLK = 32;                   // 32 q rows per block
constexpr int KVB = 32, NTILE = KVn / KVB;            // 64 kv tiles, 16/wave
constexpr float SCALE = 0.08838834764831843f;         // 1/sqrt(128)
constexpr float M0 = 16.0f;                           // fixed softmax shift
constexpr float L2E = 1.4426950408889634f;
constexpr float SCALE2 = SCALE * L2E;
constexpr float NM0L2E = -M0 * L2E;

// ws: K frag images (2 MiB) then V frag images (2 MiB); needs ws >= 4 MiB.
// K image: [bg][t][ks 0..7][lane][16B] = K[t*32+ln][ks*16+hi*8+j]
// V image: [bg][t][nt*2+ks2][lane][16B] = V[t*32+ks2*16+hi*8+j][nt*32+ln]
constexpr size_t WSK_BYTES = (size_t)Bn * Gn * NTILE * 8192;   // 2 MiB

typedef __attribute__((ext_vector_type(4))) float f32x4;
typedef __attribute__((ext_vector_type(16))) float f32x16;
typedef __attribute__((ext_vector_type(8))) __bf16 bf16x8;

union KF { f32x4 f; bf16x8 b; };

__device__ __forceinline__ unsigned pk2(float a, float b) {
  union { __bf16 h[2]; unsigned u; } x;
  x.h[0] = (__bf16)a; x.h[1] = (__bf16)b;
  return x.u;
}

__global__ __launch_bounds__(256)
void prepack(const float* __restrict__ Kg, const float* __restrict__ Vg,
             char* __restrict__ wsK, char* __restrict__ wsV) {
  const int cid = blockIdx.x * 256 + threadIdx.x;  // [0, 131072)
  const int lane = cid & 63, sub = (cid >> 6) & 7, t = (cid >> 9) & 63, bg = cid >> 15;
  const int ln = lane & 31, hi = lane >> 5;
  const size_t dst = (size_t)bg * 524288 + t * 8192 + sub * 1024 + lane * 16;
  {  // K chunk: row t*32+ln, cols sub*16 + hi*8 .. +8
    const float* src = Kg + ((size_t)bg * KVn + t * 32 + ln) * Dn + sub * 16 + hi * 8;
    float4 f0 = *(const float4*)(src);
    float4 f1 = *(const float4*)(src + 4);
    uint4 pr = make_uint4(pk2(f0.x, f0.y), pk2(f0.z, f0.w),
                          pk2(f1.x, f1.y), pk2(f1.z, f1.w));
    *(uint4*)(wsK + dst) = pr;
  }
  {  // V chunk: nt=sub>>1, ks2=sub&1: V[t*32+ks2*16+hi*8+j][nt*32+ln]
    const int nt = sub >> 1, ks2 = sub & 1;
    const float* src = Vg + ((size_t)bg * KVn + t * 32 + ks2 * 16 + hi * 8) * Dn
                       + nt * 32 + ln;
    float v[8];
#pragma unroll
    for (int j = 0; j < 8; ++j) v[j] = src[(size_t)j * Dn];
    uint4 pr = make_uint4(pk2(v[0], v[1]), pk2(v[2], v[3]),
                          pk2(v[4], v[5]), pk2(v[6], v[7]));
    *(uint4*)(wsV + dst) = pr;
  }
}

__global__ __launch_bounds__(256, 2)
void attn_fwd(const float* __restrict__ Qg, const float* __restrict__ Mg,
              const char* __restrict__ wsK, const char* __restrict__ wsV,
              float* __restrict__ Og) {
  __shared__ __align__(16) float Ol[2][4][64][16];   // 32 KB combine buffer
  __shared__ float Ls[4][32];

  const int tid = threadIdx.x;
  const int lane = tid & 63, w = tid >> 6;
  const int hi = lane >> 5, ln = lane & 31;
  const int qb = blockIdx.x * QBLK, h = blockIdx.y, b = blockIdx.z;
  const int g = h >> 4, bg = b * Gn + g;

  // ---- Q B-fragments (all waves: same 32 q rows): aq[ks][j] = Q[qb+ln][ks*16+hi*8+j]
  bf16x8 aq[8];
  {
    const float* qr = Qg + ((size_t)(b * Hn + h) * Qn + qb + ln) * Dn + hi * 8;
#pragma unroll
    for (int ks = 0; ks < 8; ++ks) {
      float4 f0 = *(const float4*)(qr + ks * 16);
      float4 f1 = *(const float4*)(qr + ks * 16 + 4);
      union { unsigned u[4]; bf16x8 b; } t;
      t.u[0] = pk2(f0.x, f0.y); t.u[1] = pk2(f0.z, f0.w);
      t.u[2] = pk2(f1.x, f1.y); t.u[3] = pk2(f1.z, f1.w);
      aq[ks] = t.b;
    }
  }
  // drain compiler-issued Q loads so the counted vm queue starts empty
  asm volatile("s_waitcnt vmcnt(0)" ::: "memory");

  const char* wsKb = wsK + (size_t)bg * 524288;
  const char* wsVb = wsV + (size_t)bg * 524288;
  const unsigned mOff = (unsigned)(((unsigned)(b * Qn + qb + ln)) * (KVn * 4) + hi * 16);

  KF kf[8], vf[8];
  f32x4 mk[4];

  auto issueKf = [&](int tg) {
    unsigned vo = (unsigned)(tg * 8192 + lane * 16);
    unsigned v2 = vo + 4096;
    asm volatile("global_load_dwordx4 %0, %1, %2"             : "=v"(kf[0].f) : "v"(vo), "s"(wsKb));
    asm volatile("global_load_dwordx4 %0, %1, %2 offset:1024" : "=v"(kf[1].f) : "v"(vo), "s"(wsKb));
    asm volatile("global_load_dwordx4 %0, %1, %2 offset:2048" : "=v"(kf[2].f) : "v"(vo), "s"(wsKb));
    asm volatile("global_load_dwordx4 %0, %1, %2 offset:3072" : "=v"(kf[3].f) : "v"(vo), "s"(wsKb));
    asm volatile("global_load_dwordx4 %0, %1, %2"             : "=v"(kf[4].f) : "v"(v2), "s"(wsKb));
    asm volatile("global_load_dwordx4 %0, %1, %2 offset:1024" : "=v"(kf[5].f) : "v"(v2), "s"(wsKb));
    asm volatile("global_load_dwordx4 %0, %1, %2 offset:2048" : "=v"(kf[6].f) : "v"(v2), "s"(wsKb));
    asm volatile("global_load_dwordx4 %0, %1, %2 offset:3072" : "=v"(kf[7].f) : "v"(v2), "s"(wsKb));
  };
  auto issueVf = [&](int tg) {
    unsigned vo = (unsigned)(tg * 8192 + lane * 16);
    unsigned v2 = vo + 4096;
    asm volatile("global_load_dwordx4 %0, %1, %2"             : "=v"(vf[0].f) : "v"(vo), "s"(wsVb));
    asm volatile("global_load_dwordx4 %0, %1, %2 offset:1024" : "=v"(vf[1].f) : "v"(vo), "s"(wsVb));
    asm volatile("global_load_dwordx4 %0, %1, %2 offset:2048" : "=v"(vf[2].f) : "v"(vo), "s"(wsVb));
    asm volatile("global_load_dwordx4 %0, %1, %2 offset:3072" : "=v"(vf[3].f) : "v"(vo), "s"(wsVb));
    asm volatile("global_load_dwordx4 %0, %1, %2"             : "=v"(vf[4].f) : "v"(v2), "s"(wsVb));
    asm volatile("global_load_dwordx4 %0, %1, %2 offset:1024" : "=v"(vf[5].f) : "v"(v2), "s"(wsVb));
    asm volatile("global_load_dwordx4 %0, %1, %2 offset:2048" : "=v"(vf[6].f) : "v"(v2), "s"(wsVb));
    asm volatile("global_load_dwordx4 %0, %1, %2 offset:3072" : "=v"(vf[7].f) : "v"(v2), "s"(wsVb));
  };
  auto issueM = [&](int tg) {
    unsigned vo = mOff + (unsigned)(tg * KVB * 4);
    asm volatile("global_load_dwordx4 %0, %1, %2"           : "=v"(mk[0]) : "v"(vo), "s"(Mg));
    asm volatile("global_load_dwordx4 %0, %1, %2 offset:32" : "=v"(mk[1]) : "v"(vo), "s"(Mg));
    asm volatile("global_load_dwordx4 %0, %1, %2 offset:64" : "=v"(mk[2]) : "v"(vo), "s"(Mg));
    asm volatile("global_load_dwordx4 %0, %1, %2 offset:96" : "=v"(mk[3]) : "v"(vo), "s"(Mg));
  };

  f32x16 o[4];
#pragma unroll
  for (int nt = 0; nt < 4; ++nt)
#pragma unroll
    for (int e = 0; e < 16; ++e) o[nt][e] = 0.0f;
  float lsum = 0.0f;

  // ---- prologue: queue = [K8][M4][V8]; wait K ----
  const int t0 = w * 16;
  issueKf(t0);
  issueM(t0);
  issueVf(t0);
  asm volatile("s_waitcnt vmcnt(12)" ::: "memory");
  asm volatile("" : "+v"(kf[0].f), "+v"(kf[1].f), "+v"(kf[2].f), "+v"(kf[3].f),
                    "+v"(kf[4].f), "+v"(kf[5].f), "+v"(kf[6].f), "+v"(kf[7].f));

  for (int tl = 0; tl < 16; ++tl) {
    const int tg = t0 + tl;
    const int tgn = (tl < 15) ? tg + 1 : tg;

    // ---- QK^T swapped: S^T[kv][q], kv=(r&3)+8*(r>>2)+4*hi, q=ln ----
    f32x16 s;
#pragma unroll
    for (int e = 0; e < 16; ++e) s[e] = 0.0f;
    __builtin_amdgcn_s_setprio(1);
#pragma unroll
    for (int ks = 0; ks < 8; ++ks)
      s = __builtin_amdgcn_mfma_f32_32x32x16_bf16(kf[ks].b, aq[ks], s, 0, 0, 0);
    __builtin_amdgcn_s_setprio(0);
    __builtin_amdgcn_sched_barrier(0);

    issueKf(tgn);   // queue: [M4][V8][K8]

    // ---- mask(tg) ready ----
    asm volatile("s_waitcnt vmcnt(16)" ::: "memory");
    asm volatile("" : "+v"(mk[0]), "+v"(mk[1]), "+v"(mk[2]), "+v"(mk[3]));

    // ---- fixed-shift softmax (exp2-folded), lane-local ----
    unsigned own[8];
    float psum = 0.0f;
#pragma unroll
    for (int gq = 0; gq < 4; ++gq) {
      float m0 = __builtin_fmaf(mk[gq][0], L2E, NM0L2E);
      float m1 = __builtin_fmaf(mk[gq][1], L2E, NM0L2E);
      float m2 = __builtin_fmaf(mk[gq][2], L2E, NM0L2E);
      float m3 = __builtin_fmaf(mk[gq][3], L2E, NM0L2E);
      float p0 = __builtin_exp2f(__builtin_fmaf(s[4 * gq + 0], SCALE2, m0));
      float p1 = __builtin_exp2f(__builtin_fmaf(s[4 * gq + 1], SCALE2, m1));
      float p2 = __builtin_exp2f(__builtin_fmaf(s[4 * gq + 2], SCALE2, m2));
      float p3 = __builtin_exp2f(__builtin_fmaf(s[4 * gq + 3], SCALE2, m3));
      psum += (p0 + p1) + (p2 + p3);
      own[2 * gq] = pk2(p0, p1);
      own[2 * gq + 1] = pk2(p2, p3);
    }
    lsum += psum;

    issueM(tgn);    // queue: [V8][K8][M4]

    // ---- P B-frags via shfl_xor: pf[ks][j] = P[q=ln][ks*16+hi*8+j] ----
    unsigned sw[8];
#pragma unroll
    for (int i = 0; i < 8; ++i) sw[i] = __shfl_xor(own[i], 32);
    union Frag { unsigned u[4]; bf16x8 b; };
    Frag pf[2];
#pragma unroll
    for (int ks = 0; ks < 2; ++ks) {
      const int bsl = ks * 4;
      pf[ks].u[0] = hi ? sw[bsl + 2] : own[bsl + 0];
      pf[ks].u[1] = hi ? sw[bsl + 3] : own[bsl + 1];
      pf[ks].u[2] = hi ? own[bsl + 2] : sw[bsl + 0];
      pf[ks].u[3] = hi ? own[bsl + 3] : sw[bsl + 1];
    }

    // ---- V(tg) ready ----
    asm volatile("s_waitcnt vmcnt(12)" ::: "memory");
    asm volatile("" : "+v"(vf[0].f), "+v"(vf[1].f), "+v"(vf[2].f), "+v"(vf[3].f),
                      "+v"(vf[4].f), "+v"(vf[5].f), "+v"(vf[6].f), "+v"(vf[7].f));

    // ---- PV swapped: o[nt] += V^T-frag x P ----
    __builtin_amdgcn_s_setprio(1);
#pragma unroll
    for (int nt = 0; nt < 4; ++nt)
#pragma unroll
      for (int ks = 0; ks < 2; ++ks)
        o[nt] = __builtin_amdgcn_mfma_f32_32x32x16_bf16(vf[nt * 2 + ks].b, pf[ks].b, o[nt], 0, 0, 0);
    __builtin_amdgcn_s_setprio(0);
    __builtin_amdgcn_sched_barrier(0);

    issueVf(tgn);   // queue: [K8][M4][V8]

    // ---- K(tgn) ready for next iteration ----
    asm volatile("s_waitcnt vmcnt(12)" ::: "memory");
    asm volatile("" : "+v"(kf[0].f), "+v"(kf[1].f), "+v"(kf[2].f), "+v"(kf[3].f),
                      "+v"(kf[4].f), "+v"(kf[5].f), "+v"(kf[6].f), "+v"(kf[7].f));
  }

  // ---- REQUIRED (r5/r6 lesson): drain ALL in-flight loads + pin dests ----
  asm volatile("s_waitcnt vmcnt(0)" ::: "memory");
  asm volatile("" : "+v"(mk[0]), "+v"(mk[1]), "+v"(mk[2]), "+v"(mk[3]));
  asm volatile("" : "+v"(vf[0].f), "+v"(vf[1].f), "+v"(vf[2].f), "+v"(vf[3].f),
                    "+v"(vf[4].f), "+v"(vf[5].f), "+v"(vf[6].f), "+v"(vf[7].f));
  asm volatile("" : "+v"(kf[0].f), "+v"(kf[1].f), "+v"(kf[2].f), "+v"(kf[3].f),
                    "+v"(kf[4].f), "+v"(kf[5].f), "+v"(kf[6].f), "+v"(kf[7].f));

  // ---- cross-wave combine (one-time): o_total = sum_w o, l_total = sum_w l ----
  const float ltot = lsum + __shfl_xor(lsum, 32);
  if (hi == 0) Ls[w][ln] = ltot;
  const int swz = (lane & 3) << 4;   // byte swizzle within 64B row
  if (w < 2) {
#pragma unroll
    for (int nt = 0; nt < 4; ++nt)
#pragma unroll
      for (int c = 0; c < 4; ++c) {
        char* p = (char*)&Ol[w][nt][lane][0] + ((c * 16) ^ swz);
        *(float4*)p = make_float4(o[nt][c * 4 + 0], o[nt][c * 4 + 1],
                                  o[nt][c * 4 + 2], o[nt][c * 4 + 3]);
      }
  }
  __syncthreads();
  if (w >= 2) {
#pragma unroll
    for (int nt = 0; nt < 4; ++nt)
#pragma unroll
      for (int c = 0; c < 4; ++c) {
        char* p = (char*)&Ol[w - 2][nt][lane][0] + ((c * 16) ^ swz);
        float4 old = *(float4*)p;
        *(float4*)p = make_float4(old.x + o[nt][c * 4 + 0], old.y + o[nt][c * 4 + 1],
                                  old.z + o[nt][c * 4 + 2], old.w + o[nt][c * 4 + 3]);
      }
  }
  __syncthreads();

  // ---- final: wave w emits d-range [w*32, w*32+32) for all 32 q rows ----
  const float linv = 1.0f / (Ls[0][ln] + Ls[1][ln] + Ls[2][ln] + Ls[3][ln]);
  float* outp = Og + (size_t)(qb + ln) * (Bn * Hn * Dn) + (size_t)b * (Hn * Dn) + h * Dn;
#pragma unroll
  for (int c = 0; c < 4; ++c) {
    const char* p0 = (const char*)&Ol[0][w][lane][0] + ((c * 16) ^ swz);
    const char* p1 = (const char*)&Ol[1][w][lane][0] + ((c * 16) ^ swz);
    float4 a = *(const float4*)p0;
    float4 bb = *(const float4*)p1;
    float4 r;
    r.x = (a.x + bb.x) * linv; r.y = (a.y + bb.y) * linv;
    r.z = (a.z + bb.z) * linv; r.w = (a.w + bb.w) * linv;
    *(float4*)(outp + w * 32 + c * 8 + hi * 4) = r;
  }
}

extern "C" void kernel_launch(void* const* d_in, const int* in_sizes, int n_in,
                              void* d_out, int out_size, void* d_ws, size_t ws_size,
                              hipStream_t stream) {
  const float* q = (const float*)d_in[0];
  const float* k = (const float*)d_in[1];
  const float* v = (const float*)d_in[2];
  const float* m = (const float*)d_in[3];
  float* out = (float*)d_out;
  char* wsK = (char*)d_ws;
  char* wsV = wsK + WSK_BYTES;

  prepack<<<dim3(512), 256, 0, stream>>>(k, v, wsK, wsV);
  dim3 grid(Qn / QBLK, Hn, Bn);
  attn_fwd<<<grid, WARPS * 64, 0, stream>>>(q, m, wsK, wsV, out);
}

// Round 10
// 245.674 us; speedup vs baseline: 1.1911x; 1.1911x over previous
//
#include <hip/hip_runtime.h>
#include <hip/hip_bf16.h>

// CoreAttention (ChatGLM GQA fallback) — swapped-operand 32x32x16 bf16 MFMA
// flash attention. Round 10: r8 structure (gll-staged pre-swizzled K/V bf16
// images, counted vmcnt, raw barrier) with KVB=64 (fixed costs amortized over
// 2x MFMA), SCALE folded into Q fragments, no softmax shift (shift-invariant;
// p bounded by 2^12, fp32 accumulates fine). Loop-exit drain+pin (r5/r6).
// B=2, H=32, G=2, Q=KV=2048, D=128, fp32 in/out.

constexpr int Bn = 2, Hn = 32, Gn = 2, Qn = 2048, KVn = 2048, Dn = 128;
constexpr int WARPS = 4, QW = 32, QBLK = WARPS * QW;  // 128 q rows / block
constexpr int KVB = 64, NT = KVn / KVB;               // 32 kv tiles of 64
constexpr int NT32 = KVn / 32;                        // 64 sub-tiles (images)
constexpr float SCALE = 0.08838834764831843f;         // 1/sqrt(128)
constexpr float L2E = 1.4426950408889634f;
constexpr float SCALE2 = SCALE * L2E;

// ws: K images (2 MiB) then V images (2 MiB); needs ws >= 4 MiB.
// K image (per bg): kv*256 + ((4*dp) ^ ((kv&15)<<4))   [256B rows, bf16]
// V image (per bg, 32-kv subtile): (d<<6) + ((vkp*4) ^ slot(d)),
//   slot(d) = (((d>>3)^(d>>1))&3)<<4
constexpr size_t WSK_BYTES = (size_t)Bn * Gn * KVn * 256;   // 2 MiB

typedef __attribute__((ext_vector_type(4))) float f32x4;
typedef __attribute__((ext_vector_type(16))) float f32x16;
typedef __attribute__((ext_vector_type(8))) __bf16 bf16x8;

__device__ __forceinline__ unsigned pk2(float a, float b) {
  union { __bf16 h[2]; unsigned u; } x;
  x.h[0] = (__bf16)a; x.h[1] = (__bf16)b;
  return x.u;
}

__global__ __launch_bounds__(256)
void prepack(const float* __restrict__ Kg, const float* __restrict__ Vg,
             char* __restrict__ wsK, char* __restrict__ wsV) {
  const int i = blockIdx.x * 256 + threadIdx.x;   // [0, 524288)
  {  // K pair: dp = d/2
    const int dp = i & 63, kv = (i >> 6) & (KVn - 1), bg = i >> 17;
    const float* src = Kg + ((size_t)bg * KVn + kv) * Dn + 2 * dp;
    const unsigned pr = pk2(src[0], src[1]);
    const size_t off = (size_t)bg * (KVn * 256) + (size_t)kv * 256
                       + ((4 * dp) ^ ((kv & 15) << 4));
    *(unsigned*)(wsK + off) = pr;
  }
  {  // V^T pair: (kv=2vkp, 2vkp+1) at row d, 32-kv subtile t
    const int d = i & 127, vg = (i >> 7) & 1023, bg = i >> 17;
    const int t = vg >> 4, vkp = vg & 15;
    const float* src = Vg + ((size_t)bg * KVn + t * 32 + 2 * vkp) * Dn + d;
    const unsigned pr = pk2(src[0], src[Dn]);
    const int slot = (((d >> 3) ^ (d >> 1)) & 3) << 4;
    const size_t off = ((size_t)bg * NT32 + t) * 8192 + (d << 6)
                       + ((vkp * 4) ^ slot);
    *(unsigned*)(wsV + off) = pr;
  }
}

__global__ __launch_bounds__(256, 2)
void attn_fwd(const float* __restrict__ Qg, const float* __restrict__ Mg,
              const char* __restrict__ wsK, const char* __restrict__ wsV,
              float* __restrict__ Og) {
  __shared__ __align__(16) short Ks[2][KVB * Dn];   // 16KB x2 (two subtiles)
  __shared__ __align__(16) short Vt[2][Dn * KVB];   // 16KB x2 (two subtiles)

  const int tid = threadIdx.x;
  const int lane = tid & 63, w = tid >> 6;
  const int hi = lane >> 5, ln = lane & 31;
  const int qb = blockIdx.x * QBLK, h = blockIdx.y, b = blockIdx.z;
  const int g = h >> 4, bg = b * Gn + g;

  // ---- Q B-fragments, PRE-SCALED by SCALE*log2(e):
  //      aq[ks][j] = Q[q = w*32+ln][ks*16 + hi*8 + j] * SCALE2
  bf16x8 aq[8];
  {
    const float* qr = Qg + ((size_t)(b * Hn + h) * Qn + qb + w * QW + ln) * Dn + hi * 8;
#pragma unroll
    for (int ks = 0; ks < 8; ++ks) {
      float4 f0 = *(const float4*)(qr + ks * 16);
      float4 f1 = *(const float4*)(qr + ks * 16 + 4);
      union { unsigned u[4]; bf16x8 b; } t;
      t.u[0] = pk2(f0.x * SCALE2, f0.y * SCALE2);
      t.u[1] = pk2(f0.z * SCALE2, f0.w * SCALE2);
      t.u[2] = pk2(f1.x * SCALE2, f1.y * SCALE2);
      t.u[3] = pk2(f1.z * SCALE2, f1.w * SCALE2);
      aq[ks] = t.b;
    }
  }
  // drain compiler-issued Q loads so the counted vm queue starts empty
  asm volatile("s_waitcnt vmcnt(0)" ::: "memory");

  const char* wsKb = wsK + (size_t)bg * (KVn * 256);
  const char* wsVb = wsV + (size_t)bg * (KVn * 256);
  const unsigned mOff = (unsigned)(((unsigned)(b * Qn + qb + w * QW + ln)) * (KVn * 4) + hi * 16);

  f32x4 mk[8];

  // stage one 64-kv tile (16KB K + 16KB V) via 8 gll per wave
  auto stageKV = [&](int tile, int buf) {
    const char* sk = wsKb + (size_t)tile * 16384 + w * 4096 + lane * 16;
    char* dk = (char*)Ks[buf] + w * 4096;
    const char* sv = wsVb + (size_t)tile * 16384 + w * 4096 + lane * 16;
    char* dv = (char*)Vt[buf] + w * 4096;
#pragma unroll
    for (int i = 0; i < 4; ++i) {
      __builtin_amdgcn_global_load_lds(
          (const __attribute__((address_space(1))) void*)(sk + i * 1024),
          (__attribute__((address_space(3))) void*)(dk + i * 1024), 16, 0, 0);
      __builtin_amdgcn_global_load_lds(
          (const __attribute__((address_space(1))) void*)(sv + i * 1024),
          (__attribute__((address_space(3))) void*)(dv + i * 1024), 16, 0, 0);
    }
  };
  auto issueM = [&](int tile) {
    unsigned vo = mOff + (unsigned)(tile * KVB * 4);
    asm volatile("global_load_dwordx4 %0, %1, %2"            : "=v"(mk[0]) : "v"(vo), "s"(Mg));
    asm volatile("global_load_dwordx4 %0, %1, %2 offset:32"  : "=v"(mk[1]) : "v"(vo), "s"(Mg));
    asm volatile("global_load_dwordx4 %0, %1, %2 offset:64"  : "=v"(mk[2]) : "v"(vo), "s"(Mg));
    asm volatile("global_load_dwordx4 %0, %1, %2 offset:96"  : "=v"(mk[3]) : "v"(vo), "s"(Mg));
    asm volatile("global_load_dwordx4 %0, %1, %2 offset:128" : "=v"(mk[4]) : "v"(vo), "s"(Mg));
    asm volatile("global_load_dwordx4 %0, %1, %2 offset:160" : "=v"(mk[5]) : "v"(vo), "s"(Mg));
    asm volatile("global_load_dwordx4 %0, %1, %2 offset:192" : "=v"(mk[6]) : "v"(vo), "s"(Mg));
    asm volatile("global_load_dwordx4 %0, %1, %2 offset:224" : "=v"(mk[7]) : "v"(vo), "s"(Mg));
  };

  f32x16 o[4];
#pragma unroll
  for (int nt = 0; nt < 4; ++nt)
#pragma unroll
    for (int e = 0; e < 16; ++e) o[nt][e] = 0.0f;
  float lsum = 0.0f;

  // ---- prologue: stage tile 0; mask(0) left in flight across barrier ----
  stageKV(0, 0);            // 8 gll
  issueM(0);                // 8 loads
  asm volatile("s_waitcnt vmcnt(8)" ::: "memory");   // gll done; M(0) flying
  __builtin_amdgcn_s_barrier();

  const int ksw = (ln & 15) << 4;

  for (int t = 0; t < NT; ++t) {
    const int cur = t & 1;
    const int tn = (t + 1 < NT) ? t + 1 : t;

    stageKV(tn, cur ^ 1);   // queue: M(t)x8 (oldest), gll x8

    // ---- QK^T swapped (two subtiles): S^T[kv][q], q=ln ----
    f32x16 s0, s1;
#pragma unroll
    for (int e = 0; e < 16; ++e) { s0[e] = 0.0f; s1[e] = 0.0f; }
    const char* ksb = (const char*)Ks[cur];
    __builtin_amdgcn_s_setprio(1);
#pragma unroll
    for (int ks = 0; ks < 8; ++ks) {
      const int byte = (ks * 32 + hi * 16) ^ ksw;
      bf16x8 k0 = *(const bf16x8*)(ksb + (ln << 8) + byte);
      bf16x8 k1 = *(const bf16x8*)(ksb + 8192 + (ln << 8) + byte);
      s0 = __builtin_amdgcn_mfma_f32_32x32x16_bf16(k0, aq[ks], s0, 0, 0, 0);
      s1 = __builtin_amdgcn_mfma_f32_32x32x16_bf16(k1, aq[ks], s1, 0, 0, 0);
    }
    __builtin_amdgcn_s_setprio(0);

    // ---- mask(t) ready (gll for t+1 still in flight) ----
    asm volatile("s_waitcnt vmcnt(8)" ::: "memory");
    asm volatile("" : "+v"(mk[0]), "+v"(mk[1]), "+v"(mk[2]), "+v"(mk[3]),
                      "+v"(mk[4]), "+v"(mk[5]), "+v"(mk[6]), "+v"(mk[7]));

    // ---- softmax: p = exp2(s*SCALE2 + mk*L2E); s already prescaled ----
    unsigned own0[8], own1[8];
    float psum = 0.0f;
#pragma unroll
    for (int gq = 0; gq < 4; ++gq) {
      float p0 = __builtin_exp2f(__builtin_fmaf(mk[gq][0], L2E, s0[4 * gq + 0]));
      float p1 = __builtin_exp2f(__builtin_fmaf(mk[gq][1], L2E, s0[4 * gq + 1]));
      float p2 = __builtin_exp2f(__builtin_fmaf(mk[gq][2], L2E, s0[4 * gq + 2]));
      float p3 = __builtin_exp2f(__builtin_fmaf(mk[gq][3], L2E, s0[4 * gq + 3]));
      float q0 = __builtin_exp2f(__builtin_fmaf(mk[4 + gq][0], L2E, s1[4 * gq + 0]));
      float q1 = __builtin_exp2f(__builtin_fmaf(mk[4 + gq][1], L2E, s1[4 * gq + 1]));
      float q2 = __builtin_exp2f(__builtin_fmaf(mk[4 + gq][2], L2E, s1[4 * gq + 2]));
      float q3 = __builtin_exp2f(__builtin_fmaf(mk[4 + gq][3], L2E, s1[4 * gq + 3]));
      psum += ((p0 + p1) + (p2 + p3)) + ((q0 + q1) + (q2 + q3));
      own0[2 * gq] = pk2(p0, p1); own0[2 * gq + 1] = pk2(p2, p3);
      own1[2 * gq] = pk2(q0, q1); own1[2 * gq + 1] = pk2(q2, q3);
    }
    lsum += psum;

    issueM(tn);   // queue: gll x8 (oldest), M(t+1) x8

    // ---- P B-frags via shfl_xor (r2-verified): pf[ks][j]=P[q][ks*16+hi*8+j]
    unsigned sw0[8], sw1[8];
#pragma unroll
    for (int i = 0; i < 8; ++i) {
      sw0[i] = __shfl_xor(own0[i], 32);
      sw1[i] = __shfl_xor(own1[i], 32);
    }
    union Frag { unsigned u[4]; bf16x8 b; };
    Frag pf[4];
#pragma unroll
    for (int ks = 0; ks < 4; ++ks) {
      const unsigned* ow = (ks < 2) ? own0 : own1;
      const unsigned* sw = (ks < 2) ? sw0 : sw1;
      const int bsl = (ks & 1) * 4;
      pf[ks].u[0] = hi ? sw[bsl + 2] : ow[bsl + 0];
      pf[ks].u[1] = hi ? sw[bsl + 3] : ow[bsl + 1];
      pf[ks].u[2] = hi ? ow[bsl + 2] : sw[bsl + 0];
      pf[ks].u[3] = hi ? ow[bsl + 3] : sw[bsl + 1];
    }

    // ---- PV swapped: O^T[d][q] += V^T · P (ks 0,1 sub0; 2,3 sub1) ----
    const char* vtb = (const char*)Vt[cur];
    __builtin_amdgcn_s_setprio(1);
#pragma unroll
    for (int nt = 0; nt < 4; ++nt) {
      const int d = nt * 32 + ln;
      const int swz = (((d >> 3) ^ (d >> 1)) & 3) << 4;
#pragma unroll
      for (int ks = 0; ks < 4; ++ks) {
        const int base = (ks >> 1) * 8192 + (d << 6);
        bf16x8 vfr = *(const bf16x8*)(vtb + base + (((ks & 1) * 32 + hi * 16) ^ swz));
        o[nt] = __builtin_amdgcn_mfma_f32_32x32x16_bf16(vfr, pf[ks].b, o[nt], 0, 0, 0);
      }
    }
    __builtin_amdgcn_s_setprio(0);

    // ---- gll for t+1 landed (M(t+1) stays in flight); sync ----
    asm volatile("s_waitcnt vmcnt(8)" ::: "memory");
    asm volatile("s_waitcnt lgkmcnt(0)" ::: "memory");
    __builtin_amdgcn_s_barrier();   // raw: vmcnt NOT drained (mask in flight)
  }

  // ---- REQUIRED (r5/r6 lesson): drain in-flight mask loads + pin dests ----
  asm volatile("s_waitcnt vmcnt(0)" ::: "memory");
  asm volatile("" : "+v"(mk[0]), "+v"(mk[1]), "+v"(mk[2]), "+v"(mk[3]),
                    "+v"(mk[4]), "+v"(mk[5]), "+v"(mk[6]), "+v"(mk[7]));

  // ---- epilogue: O^T/l, write context[q][b][h*128+d] ----
  const float ltot = lsum + __shfl_xor(lsum, 32);
  const float invl = 1.0f / ltot;
  float* outp = Og + (size_t)(qb + w * QW + ln) * (Bn * Hn * Dn) + (size_t)b * (Hn * Dn) + h * Dn;
#pragma unroll
  for (int nt = 0; nt < 4; ++nt)
#pragma unroll
    for (int gq = 0; gq < 4; ++gq) {
      float4 v;
      v.x = o[nt][gq * 4 + 0] * invl;
      v.y = o[nt][gq * 4 + 1] * invl;
      v.z = o[nt][gq * 4 + 2] * invl;
      v.w = o[nt][gq * 4 + 3] * invl;
      *(float4*)(outp + nt * 32 + gq * 8 + hi * 4) = v;
    }
}

extern "C" void kernel_launch(void* const* d_in, const int* in_sizes, int n_in,
                              void* d_out, int out_size, void* d_ws, size_t ws_size,
                              hipStream_t stream) {
  const float* q = (const float*)d_in[0];
  const float* k = (const float*)d_in[1];
  const float* v = (const float*)d_in[2];
  const float* m = (const float*)d_in[3];
  float* out = (float*)d_out;
  char* wsK = (char*)d_ws;
  char* wsV = wsK + WSK_BYTES;

  prepack<<<dim3((Bn * Gn * KVn * 64) / 256), 256, 0, stream>>>(k, v, wsK, wsV);
  dim3 grid(Qn / QBLK, Hn, Bn);
  attn_fwd<<<grid, WARPS * 64, 0, stream>>>(q, m, wsK, wsV, out);
}

// Round 11
// 241.080 us; speedup vs baseline: 1.2138x; 1.0191x over previous
//
#include <hip/hip_runtime.h>
#include <hip/hip_bf16.h>

// CoreAttention (ChatGLM GQA fallback) — swapped-operand 32x32x16 bf16 MFMA
// flash attention. Round 11: head-quad blocks — 4 heads (same kv-group) x the
// SAME 32 q rows; K, V, and the mask tile are shared by all 4 waves. All
// staging via global_load_lds from pre-swizzled images (K/V prepacked bf16 in
// d_ws; mask direct from fp32 input with per-lane pre-swizzled source). No
// register-dest async loads at all -> __syncthreads() is the only sync.
// Q pre-scaled by SCALE*log2e; no softmax shift (shift-invariant, bounded).
// B=2, H=32, G=2, Q=KV=2048, D=128, fp32 in/out.

constexpr int Bn = 2, Hn = 32, Gn = 2, Qn = 2048, KVn = 2048, Dn = 128;
constexpr int WARPS = 4, QBLK = 32, HQ = 4;           // 32 q rows, 4 heads/blk
constexpr int KVB = 32, NT = KVn / KVB;               // 64 kv tiles
constexpr int NT32 = KVn / 32;
constexpr float SCALE = 0.08838834764831843f;         // 1/sqrt(128)
constexpr float L2E = 1.4426950408889634f;
constexpr float SCALE2 = SCALE * L2E;

// ws: K images (2 MiB) then V images (2 MiB); needs ws >= 4 MiB.
// K image (per bg): kv*256 + ((4*dp) ^ ((kv&15)<<4))   [256B rows, bf16]
// V image (per bg, 32-kv subtile): (d<<6) + ((vkp*4) ^ slot(d)),
//   slot(d) = (((d>>3)^(d>>1))&3)<<4
constexpr size_t WSK_BYTES = (size_t)Bn * Gn * KVn * 256;   // 2 MiB

typedef __attribute__((ext_vector_type(16))) float f32x16;
typedef __attribute__((ext_vector_type(8))) __bf16 bf16x8;

__device__ __forceinline__ unsigned pk2(float a, float b) {
  union { __bf16 h[2]; unsigned u; } x;
  x.h[0] = (__bf16)a; x.h[1] = (__bf16)b;
  return x.u;
}

__global__ __launch_bounds__(256)
void prepack(const float* __restrict__ Kg, const float* __restrict__ Vg,
             char* __restrict__ wsK, char* __restrict__ wsV) {
  const int i = blockIdx.x * 256 + threadIdx.x;   // [0, 524288)
  {  // K pair: dp = d/2
    const int dp = i & 63, kv = (i >> 6) & (KVn - 1), bg = i >> 17;
    const float* src = Kg + ((size_t)bg * KVn + kv) * Dn + 2 * dp;
    const unsigned pr = pk2(src[0], src[1]);
    const size_t off = (size_t)bg * (KVn * 256) + (size_t)kv * 256
                       + ((4 * dp) ^ ((kv & 15) << 4));
    *(unsigned*)(wsK + off) = pr;
  }
  {  // V^T pair: (kv=2vkp, 2vkp+1) at row d, 32-kv subtile t
    const int d = i & 127, vg = (i >> 7) & 1023, bg = i >> 17;
    const int t = vg >> 4, vkp = vg & 15;
    const float* src = Vg + ((size_t)bg * KVn + t * 32 + 2 * vkp) * Dn + d;
    const unsigned pr = pk2(src[0], src[Dn]);
    const int slot = (((d >> 3) ^ (d >> 1)) & 3) << 4;
    const size_t off = ((size_t)bg * NT32 + t) * 8192 + (d << 6)
                       + ((vkp * 4) ^ slot);
    *(unsigned*)(wsV + off) = pr;
  }
}

__global__ __launch_bounds__(256, 3)
void attn_fwd(const float* __restrict__ Qg, const float* __restrict__ Mg,
              const char* __restrict__ wsK, const char* __restrict__ wsV,
              float* __restrict__ Og) {
  __shared__ __align__(16) short Ks[2][KVB * Dn];    // 8KB x2
  __shared__ __align__(16) short Vt[2][Dn * KVB];    // 8KB x2
  __shared__ __align__(16) float Ms[2][QBLK * KVB];  // 4KB x2 (swizzled rows)

  const int tid = threadIdx.x;
  const int lane = tid & 63, w = tid >> 6;
  const int hi = lane >> 5, ln = lane & 31;
  const int qb = blockIdx.x * QBLK, hq = blockIdx.y, b = blockIdx.z;
  const int h0 = hq * HQ, h = h0 + w;                // wave's head
  const int g = h0 >> 4, bg = b * Gn + g;            // quad shares g

  // ---- Q B-fragments, PRE-SCALED: aq[ks][j] = Q[h][qb+ln][ks*16+hi*8+j]*SCALE2
  bf16x8 aq[8];
  {
    const float* qr = Qg + ((size_t)(b * Hn + h) * Qn + qb + ln) * Dn + hi * 8;
#pragma unroll
    for (int ks = 0; ks < 8; ++ks) {
      float4 f0 = *(const float4*)(qr + ks * 16);
      float4 f1 = *(const float4*)(qr + ks * 16 + 4);
      union { unsigned u[4]; bf16x8 b; } t;
      t.u[0] = pk2(f0.x * SCALE2, f0.y * SCALE2);
      t.u[1] = pk2(f0.z * SCALE2, f0.w * SCALE2);
      t.u[2] = pk2(f1.x * SCALE2, f1.y * SCALE2);
      t.u[3] = pk2(f1.z * SCALE2, f1.w * SCALE2);
      aq[ks] = t.b;
    }
  }

  const char* wsKb = wsK + (size_t)bg * (KVn * 256);
  const char* wsVb = wsV + (size_t)bg * (KVn * 256);
  // mask stage geometry: wave w covers rows w*8..w*8+7 (128B each)
  const int mr = w * 8 + (lane >> 3);               // q row within tile
  const int mc = (lane & 7) << 4;                   // 16B slot within row
  const char* mSrcBase = (const char*)Mg + (size_t)(b * Qn + qb + mr) * (KVn * 4)
                         + (mc ^ ((mr & 7) << 4));  // pre-swizzled source

  auto stage = [&](int tile, int buf) {
    const char* sk = wsKb + (size_t)tile * 8192 + w * 2048 + lane * 16;
    char* dk = (char*)Ks[buf] + w * 2048;
    const char* sv = wsVb + (size_t)tile * 8192 + w * 2048 + lane * 16;
    char* dv = (char*)Vt[buf] + w * 2048;
    __builtin_amdgcn_global_load_lds(
        (const __attribute__((address_space(1))) void*)sk,
        (__attribute__((address_space(3))) void*)dk, 16, 0, 0);
    __builtin_amdgcn_global_load_lds(
        (const __attribute__((address_space(1))) void*)(sk + 1024),
        (__attribute__((address_space(3))) void*)(dk + 1024), 16, 0, 0);
    __builtin_amdgcn_global_load_lds(
        (const __attribute__((address_space(1))) void*)sv,
        (__attribute__((address_space(3))) void*)dv, 16, 0, 0);
    __builtin_amdgcn_global_load_lds(
        (const __attribute__((address_space(1))) void*)(sv + 1024),
        (__attribute__((address_space(3))) void*)(dv + 1024), 16, 0, 0);
    const char* sm = mSrcBase + tile * 128;
    char* dm = (char*)Ms[buf] + w * 1024;
    __builtin_amdgcn_global_load_lds(
        (const __attribute__((address_space(1))) void*)sm,
        (__attribute__((address_space(3))) void*)dm, 16, 0, 0);
  };

  f32x16 o[4];
#pragma unroll
  for (int nt = 0; nt < 4; ++nt)
#pragma unroll
    for (int e = 0; e < 16; ++e) o[nt][e] = 0.0f;
  float lsum = 0.0f;

  // ---- prologue ----
  stage(0, 0);
  __syncthreads();

  const int ksw = (ln & 15) << 4;
  const int msw = (ln & 7) << 4;

  for (int t = 0; t < NT; ++t) {
    const int cur = t & 1;
    const int tn = (t + 1 < NT) ? t + 1 : t;

    stage(tn, cur ^ 1);     // prefetch next tile (gll; covered by tile body)
    __builtin_amdgcn_sched_barrier(0);

    // ---- QK^T swapped: S^T[kv][q], kv=(r&3)+8*(r>>2)+4*hi, q=ln ----
    f32x16 s;
#pragma unroll
    for (int e = 0; e < 16; ++e) s[e] = 0.0f;
    const char* ksb = (const char*)Ks[cur];
    __builtin_amdgcn_s_setprio(1);
#pragma unroll
    for (int ks = 0; ks < 8; ++ks) {
      bf16x8 k0 = *(const bf16x8*)(ksb + (ln << 8) + ((ks * 32 + hi * 16) ^ ksw));
      s = __builtin_amdgcn_mfma_f32_32x32x16_bf16(k0, aq[ks], s, 0, 0, 0);
    }
    __builtin_amdgcn_s_setprio(0);

    // ---- softmax: p = exp2(s + mk*L2E); mask from LDS (swizzled rows) ----
    const char* msb = (const char*)Ms[cur] + ln * 128;
    unsigned own[8];
    float psum = 0.0f;
#pragma unroll
    for (int gq = 0; gq < 4; ++gq) {
      float4 mkq = *(const float4*)(msb + ((gq * 32 + hi * 16) ^ msw));
      float p0 = __builtin_exp2f(__builtin_fmaf(mkq.x, L2E, s[4 * gq + 0]));
      float p1 = __builtin_exp2f(__builtin_fmaf(mkq.y, L2E, s[4 * gq + 1]));
      float p2 = __builtin_exp2f(__builtin_fmaf(mkq.z, L2E, s[4 * gq + 2]));
      float p3 = __builtin_exp2f(__builtin_fmaf(mkq.w, L2E, s[4 * gq + 3]));
      psum += (p0 + p1) + (p2 + p3);
      own[2 * gq] = pk2(p0, p1);
      own[2 * gq + 1] = pk2(p2, p3);
    }
    lsum += psum;

    // ---- P B-frags via shfl_xor (verified): pf[ks][j]=P[q][ks*16+hi*8+j] ----
    unsigned sw[8];
#pragma unroll
    for (int i = 0; i < 8; ++i) sw[i] = __shfl_xor(own[i], 32);
    union Frag { unsigned u[4]; bf16x8 b; };
    Frag pf[2];
#pragma unroll
    for (int ks = 0; ks < 2; ++ks) {
      const int bsl = ks * 4;
      pf[ks].u[0] = hi ? sw[bsl + 2] : own[bsl + 0];
      pf[ks].u[1] = hi ? sw[bsl + 3] : own[bsl + 1];
      pf[ks].u[2] = hi ? own[bsl + 2] : sw[bsl + 0];
      pf[ks].u[3] = hi ? own[bsl + 3] : sw[bsl + 1];
    }

    // ---- PV swapped: O^T[d][q] += V^T · P ----
    const char* vtb = (const char*)Vt[cur];
    __builtin_amdgcn_s_setprio(1);
#pragma unroll
    for (int nt = 0; nt < 4; ++nt) {
      const int d = nt * 32 + ln;
      const int swz = (((d >> 3) ^ (d >> 1)) & 3) << 4;
#pragma unroll
      for (int ks = 0; ks < 2; ++ks) {
        bf16x8 vfr = *(const bf16x8*)(vtb + (d << 6) + (((ks * 32 + hi * 16)) ^ swz));
        o[nt] = __builtin_amdgcn_mfma_f32_32x32x16_bf16(vfr, pf[ks].b, o[nt], 0, 0, 0);
      }
    }
    __builtin_amdgcn_s_setprio(0);

    // one barrier per tile; drains vmcnt (gll for t+1 done) + lgkmcnt
    __syncthreads();
  }

  // ---- epilogue: O^T/l, write context[q][b][h*128+d] ----
  const float ltot = lsum + __shfl_xor(lsum, 32);
  const float invl = 1.0f / ltot;
  float* outp = Og + (size_t)(qb + ln) * (Bn * Hn * Dn) + (size_t)b * (Hn * Dn) + h * Dn;
#pragma unroll
  for (int nt = 0; nt < 4; ++nt)
#pragma unroll
    for (int gq = 0; gq < 4; ++gq) {
      float4 v;
      v.x = o[nt][gq * 4 + 0] * invl;
      v.y = o[nt][gq * 4 + 1] * invl;
      v.z = o[nt][gq * 4 + 2] * invl;
      v.w = o[nt][gq * 4 + 3] * invl;
      *(float4*)(outp + nt * 32 + gq * 8 + hi * 4) = v;
    }
}

extern "C" void kernel_launch(void* const* d_in, const int* in_sizes, int n_in,
                              void* d_out, int out_size, void* d_ws, size_t ws_size,
                              hipStream_t stream) {
  const float* q = (const float*)d_in[0];
  const float* k = (const float*)d_in[1];
  const float* v = (const float*)d_in[2];
  const float* m = (const float*)d_in[3];
  float* out = (float*)d_out;
  char* wsK = (char*)d_ws;
  char* wsV = wsK + WSK_BYTES;

  prepack<<<dim3((Bn * Gn * KVn * 64) / 256), 256, 0, stream>>>(k, v, wsK, wsV);
  dim3 grid(Qn / QBLK, Hn / HQ, Bn);
  attn_fwd<<<grid, WARPS * 64, 0, stream>>>(q, m, wsK, wsV, out);
}